// Round 10
// baseline (179.157 us; speedup 1.0000x reference)
//
#include <hip/hip_runtime.h>

// Fused single-pass 3x3 VALID conv via bf16 MFMA implicit GEMM.
// x:(16,2048,2048) fp32, k:(16,16,3,3) fp32 -> out:(16,2046,2046) fp32
// Staging is 2-step to keep HBM latency OUT of registers:
//   (1) global_load_lds the fp32 tile slice (8 ci) into an LDS f32 region
//       (no VGPR round-trip, proven-fast path);
//   (2) LDS->LDS convert: ds_read_b128 (4w x 1ci) -> pk2 -> ds_write_b128
//       into the bf16 [row][col][ci] region (XOR-swizzled), fully pipelined.
// Two ci-half slices reuse the f32 region. Compute: 5x mfma_16x16x32_bf16
// per 16x16 sub-tile (K = tap*16+ci padded 144->160, dead K = zero weights).
// Weight fragments precomputed once into d_ws.

#define HIN   2048
#define WIN   2048
#define HOUT  2046
#define WOUT  2046
#define PLANE_IN  (HIN * WIN)
#define PLANE_OUT (HOUT * WOUT)
#define TR 34
#define TC 36                          // bf16 region col stride
#define BF16_U32 (TR * TC * 8)         // 9792 u32 = 39168 B
#define F32_U32  9792                  // f32 region offset (u32); 2448 chunks
#define LDS_BYTES ((BF16_U32 + 2448 * 4) * 4)   // 78336 B
#define WF_U32 (5 * 64 * 4)            // weight-frag buffer (5 KiB)

typedef __attribute__((ext_vector_type(8))) short bf16x8;
typedef __attribute__((ext_vector_type(4))) float f32x4;
typedef __attribute__((ext_vector_type(4))) unsigned u32x4;
typedef f32x4 __attribute__((aligned(4))) f32x4_u;

static __device__ __forceinline__ short f2bf(float f) {
    unsigned u = __float_as_uint(f);
    return (short)((u + 0x7FFFu + ((u >> 16) & 1u)) >> 16);   // RNE
}
static __device__ __forceinline__ unsigned pk2(float lo, float hi) {
    unsigned a = __float_as_uint(lo);
    unsigned b = __float_as_uint(hi);
    a = (a + 0x7FFFu + ((a >> 16) & 1u)) >> 16;
    b = (b + 0x7FFFu + ((b >> 16) & 1u)) & 0xFFFF0000u;
    return a | b;
}

// ---------------- setup: per-lane MFMA weight fragments ----------------------
__global__ __launch_bounds__(64)
void wf_setup(const float* __restrict__ k, unsigned* __restrict__ wfbuf) {
    int lane = threadIdx.x;
    int m = lane & 15, g = lane >> 4;
    #pragma unroll
    for (int i = 0; i < 5; ++i) {
        u32x4 q;
        #pragma unroll
        for (int jj = 0; jj < 4; ++jj) {
            unsigned r = 0;
            #pragma unroll
            for (int e = 0; e < 2; ++e) {
                int kk  = 32 * i + 8 * g + 2 * jj + e;
                int tap = kk >> 4;
                int ci  = kk & 15;
                unsigned v = 0;
                if (tap < 9) v = (unsigned short)f2bf(k[(m * 16 + ci) * 9 + tap]);
                r |= v << (16 * e);
            }
            q[jj] = r;
        }
        *(u32x4*)(wfbuf + (i * 64 + lane) * 4) = q;
    }
}

// ---------------- fused conv: gll fp32 + LDS-bounce convert ------------------
__global__ __launch_bounds__(512, 4)
void conv3x3_gllb(const float* __restrict__ x,
                  const unsigned* __restrict__ wfbuf,
                  float* __restrict__ out) {
    extern __shared__ unsigned lds[];   // [0,9792): bf16 tile; [9792,19584): f32 slice

    const int tid  = threadIdx.x;
    const int lane = tid & 63;
    const int wv   = tid >> 6;
    const int m    = lane & 15;
    const int g    = lane >> 4;

    int bid = blockIdx.x;                      // 4096 blocks (64 x 64 tiles)
    int swz = (bid & 7) * 512 + (bid >> 3);    // XCD-chunked (4096 % 8 == 0)
    int h0 = (swz >> 6) * 32; if (h0 > HOUT - 32) h0 = HOUT - 32;  // 2014
    int w0 = (swz & 63) * 32;

    // f32 slice layout: chunk l = row*72 + ci*9 + q  (ci in slice, q = w-quad)
    // 2448 chunks of 16B; gll deposits linearly at F32_U32 + l*16B.
#define STAGE_GLL(S) do {                                                     \
        _Pragma("unroll")                                                     \
        for (int rnd = 0; rnd < 5; ++rnd) {                                   \
            if (rnd < 4 || tid < 400) {                                       \
                int l   = rnd * 512 + tid;                                    \
                int row = l / 72;                                             \
                int rem = l - row * 72;                                       \
                int ci  = rem / 9;                                            \
                int q   = rem - ci * 9;                                       \
                int w   = w0 + q * 4; if (w > WIN - 4) w = WIN - 4;           \
                const float* src = x + (size_t)((S) * 8 + ci) * PLANE_IN      \
                                     + (size_t)(h0 + row) * WIN + w;          \
                __builtin_amdgcn_global_load_lds(                             \
                    (const __attribute__((address_space(1))) unsigned*)src,   \
                    (__attribute__((address_space(3))) unsigned*)             \
                        (lds + F32_U32 + (rnd * 512 + wv * 64) * 4),          \
                    16, 0, 0);                                                \
            }                                                                 \
        }                                                                     \
    } while (0)

    // convert: task (row,q) reads 8 ci x f32x4 from LDS, packs, writes the
    // cih-half 16B chunks of 4 positions (XOR-swizzled, matches compute).
#define CONVERT(S) do {                                                      \
        if (tid < TR * 9) {                                                  \
            int row = tid / 9;                                               \
            int q   = tid - row * 9;                                         \
            const char* fb = (const char*)(lds + F32_U32);                   \
            f32x4 v0 = *(const f32x4*)(fb + (row * 72 + 0 * 9 + q) * 16);    \
            f32x4 v1 = *(const f32x4*)(fb + (row * 72 + 1 * 9 + q) * 16);    \
            f32x4 v2 = *(const f32x4*)(fb + (row * 72 + 2 * 9 + q) * 16);    \
            f32x4 v3 = *(const f32x4*)(fb + (row * 72 + 3 * 9 + q) * 16);    \
            f32x4 v4 = *(const f32x4*)(fb + (row * 72 + 4 * 9 + q) * 16);    \
            f32x4 v5 = *(const f32x4*)(fb + (row * 72 + 5 * 9 + q) * 16);    \
            f32x4 v6 = *(const f32x4*)(fb + (row * 72 + 6 * 9 + q) * 16);    \
            f32x4 v7 = *(const f32x4*)(fb + (row * 72 + 7 * 9 + q) * 16);    \
            int c = 4 * q;                                                   \
            int a = ((row * TC + c) * 32 + (S) * 16) ^ ((c & 4) << 2);       \
            u32x4 ch;                                                        \
            ch[0] = pk2(v0[0], v1[0]); ch[1] = pk2(v2[0], v3[0]);            \
            ch[2] = pk2(v4[0], v5[0]); ch[3] = pk2(v6[0], v7[0]);            \
            *(u32x4*)((char*)lds + a)      = ch;                             \
            ch[0] = pk2(v0[1], v1[1]); ch[1] = pk2(v2[1], v3[1]);            \
            ch[2] = pk2(v4[1], v5[1]); ch[3] = pk2(v6[1], v7[1]);            \
            *(u32x4*)((char*)lds + a + 32) = ch;                             \
            ch[0] = pk2(v0[2], v1[2]); ch[1] = pk2(v2[2], v3[2]);            \
            ch[2] = pk2(v4[2], v5[2]); ch[3] = pk2(v6[2], v7[2]);            \
            *(u32x4*)((char*)lds + a + 64) = ch;                             \
            ch[0] = pk2(v0[3], v1[3]); ch[1] = pk2(v2[3], v3[3]);            \
            ch[2] = pk2(v4[3], v5[3]); ch[3] = pk2(v6[3], v7[3]);            \
            *(u32x4*)((char*)lds + a + 96) = ch;                             \
        }                                                                    \
    } while (0)

    // weight fragments: 5 coalesced 16B loads (independent of staging)
    bf16x8 wf[5];
    #pragma unroll
    for (int i = 0; i < 5; ++i)
        wf[i] = *(const bf16x8*)(wfbuf + (i * 64 + lane) * 4);

    // per-lane A-fragment LDS byte offsets
    int off[5];
    #pragma unroll
    for (int i = 0; i < 5; ++i) {
        int tap = 2 * i + (g >> 1);
        if (tap > 8) tap = 8;                   // dead K (weights are 0)
        int kh = tap / 3;
        int kw = tap - kh * 3;
        int col = m + kw;
        int o = (kh * TC + col) * 32 + (g & 1) * 16;
        off[i] = o ^ ((col & 4) << 2);          // matches convert swizzle
    }

    STAGE_GLL(0);
    __syncthreads();          // drains gll vmcnt
    CONVERT(0);
    __syncthreads();          // f32 region free for reuse
    STAGE_GLL(1);
    __syncthreads();
    CONVERT(1);
    __syncthreads();          // bf16 tile complete

#undef STAGE_GLL
#undef CONVERT

    const char* ldsb = (const char*)lds;

    #pragma unroll
    for (int hl4 = 0; hl4 < 4; ++hl4) {
        int hl = wv * 4 + hl4;                  // h always < HOUT (h0 <= 2014)
        int h  = h0 + hl;
        #pragma unroll
        for (int nh = 0; nh < 2; ++nh) {
            int wl = nh * 16;
            int tb = (hl * TC + wl) * 32;
            f32x4 acc = {0.f, 0.f, 0.f, 0.f};
            #pragma unroll
            for (int i = 0; i < 5; ++i) {
                bf16x8 a = *(const bf16x8*)(ldsb + (tb + off[i]));
                acc = __builtin_amdgcn_mfma_f32_16x16x32_bf16(a, wf[i], acc, 0, 0, 0);
            }
            // D: row = g*4+r = spatial, col = m = co  ->  float4 store
            int w = w0 + wl + g * 4;
            float* op = out + m * (size_t)PLANE_OUT + (size_t)h * WOUT + w;
            if (w + 3 < WOUT) {
                *(f32x4_u*)op = acc;
            } else {
                #pragma unroll
                for (int r = 0; r < 4; ++r)
                    if (w + r < WOUT) op[r] = acc[r];
            }
        }
    }
}

// ---------------- fallback A: reg-staged fused (R8, proven 157us) ------------
__global__ __launch_bounds__(512, 8)
void conv3x3_fused(const float* __restrict__ x,
                   const unsigned* __restrict__ wfbuf,
                   float* __restrict__ out) {
    __shared__ unsigned lds[TR * TC * 8];

    const int tid  = threadIdx.x;
    const int lane = tid & 63;
    const int wv   = tid >> 6;
    const int m    = lane & 15;
    const int g    = lane >> 4;

    int bid = blockIdx.x;
    int swz = (bid & 7) * 512 + (bid >> 3);
    int h0 = (swz >> 6) * 32; if (h0 > HOUT - 32) h0 = HOUT - 32;
    int w0 = (swz & 63) * 32;

#define STAGE_TASK(T) do {                                                    \
        int t   = (T);                                                        \
        int q   = t % 9;                                                      \
        int r2  = t / 9;                                                      \
        int cih = r2 & 1;                                                     \
        int row = r2 >> 1;                                                    \
        int c   = 4 * q;                                                      \
        int w   = w0 + c; if (w > WIN - 4) w = WIN - 4;                       \
        const float* gp = x + (size_t)(cih * 8) * PLANE_IN                    \
                            + (size_t)(h0 + row) * WIN + w;                   \
        f32x4 f0 = *(const f32x4*)(gp + 0 * (size_t)PLANE_IN);                \
        f32x4 f1 = *(const f32x4*)(gp + 1 * (size_t)PLANE_IN);                \
        f32x4 f2 = *(const f32x4*)(gp + 2 * (size_t)PLANE_IN);                \
        f32x4 f3 = *(const f32x4*)(gp + 3 * (size_t)PLANE_IN);                \
        f32x4 f4 = *(const f32x4*)(gp + 4 * (size_t)PLANE_IN);                \
        f32x4 f5 = *(const f32x4*)(gp + 5 * (size_t)PLANE_IN);                \
        f32x4 f6 = *(const f32x4*)(gp + 6 * (size_t)PLANE_IN);                \
        f32x4 f7 = *(const f32x4*)(gp + 7 * (size_t)PLANE_IN);                \
        int a = ((row * TC + c) * 32 + cih * 16) ^ ((c & 4) << 2);            \
        u32x4 ch;                                                             \
        ch[0] = pk2(f0[0], f1[0]); ch[1] = pk2(f2[0], f3[0]);                 \
        ch[2] = pk2(f4[0], f5[0]); ch[3] = pk2(f6[0], f7[0]);                 \
        *(u32x4*)((char*)lds + a)      = ch;                                  \
        ch[0] = pk2(f0[1], f1[1]); ch[1] = pk2(f2[1], f3[1]);                 \
        ch[2] = pk2(f4[1], f5[1]); ch[3] = pk2(f6[1], f7[1]);                 \
        *(u32x4*)((char*)lds + a + 32) = ch;                                  \
        ch[0] = pk2(f0[2], f1[2]); ch[1] = pk2(f2[2], f3[2]);                 \
        ch[2] = pk2(f4[2], f5[2]); ch[3] = pk2(f6[2], f7[2]);                 \
        *(u32x4*)((char*)lds + a + 64) = ch;                                  \
        ch[0] = pk2(f0[3], f1[3]); ch[1] = pk2(f2[3], f3[3]);                 \
        ch[2] = pk2(f4[3], f5[3]); ch[3] = pk2(f6[3], f7[3]);                 \
        *(u32x4*)((char*)lds + a + 96) = ch;                                  \
    } while (0)

    STAGE_TASK(tid);
    if (tid < TR * 9 * 2 - 512) STAGE_TASK(512 + tid);
#undef STAGE_TASK

    bf16x8 wf[5];
    #pragma unroll
    for (int i = 0; i < 5; ++i)
        wf[i] = *(const bf16x8*)(wfbuf + (i * 64 + lane) * 4);

    int off[5];
    #pragma unroll
    for (int i = 0; i < 5; ++i) {
        int tap = 2 * i + (g >> 1);
        if (tap > 8) tap = 8;
        int kh = tap / 3;
        int kw = tap - kh * 3;
        int col = m + kw;
        int o = (kh * TC + col) * 32 + (g & 1) * 16;
        off[i] = o ^ ((col & 4) << 2);
    }

    __syncthreads();

    const char* ldsb = (const char*)lds;

    #pragma unroll
    for (int hl4 = 0; hl4 < 4; ++hl4) {
        int hl = wv * 4 + hl4;
        int h  = h0 + hl;
        #pragma unroll
        for (int nh = 0; nh < 2; ++nh) {
            int wl = nh * 16;
            int tb = (hl * TC + wl) * 32;
            f32x4 acc = {0.f, 0.f, 0.f, 0.f};
            #pragma unroll
            for (int i = 0; i < 5; ++i) {
                bf16x8 a = *(const bf16x8*)(ldsb + (tb + off[i]));
                acc = __builtin_amdgcn_mfma_f32_16x16x32_bf16(a, wf[i], acc, 0, 0, 0);
            }
            int w = w0 + wl + g * 4;
            float* op = out + m * (size_t)PLANE_OUT + (size_t)h * WOUT + w;
            if (w + 3 < WOUT) {
                *(f32x4_u*)op = acc;
            } else {
                #pragma unroll
                for (int r = 0; r < 4; ++r)
                    if (w + r < WOUT) op[r] = acc[r];
            }
        }
    }
}

// ---------------- fallback B (no workspace): fp32-staged single pass ---------
__global__ __launch_bounds__(256, 4)
void conv3x3_mfma(const float* __restrict__ x,
                  const float* __restrict__ k,
                  float* __restrict__ out) {
    __shared__ short lds[TR * 34 * 16];
    const int tid  = threadIdx.x;
    const int lane = tid & 63;
    const int wv   = tid >> 6;
    const int m    = lane & 15;
    const int g    = lane >> 4;
    int bid = blockIdx.x;
    int swz = (bid & 7) * 512 + (bid >> 3);
    int h0 = (swz >> 6) * 32;
    int w0 = (swz & 63) * 32;
    for (int p = tid; p < TR * 34; p += 256) {
        int r = p / 34, c = p - r * 34;
        int hh = h0 + r; if (hh > HIN - 1) hh = HIN - 1;
        int ww = w0 + c; if (ww > WIN - 1) ww = WIN - 1;
        const float* gp = x + hh * WIN + ww;
        short t[16];
        #pragma unroll
        for (int ci = 0; ci < 16; ++ci) t[ci] = f2bf(gp[ci * PLANE_IN]);
        bf16x8 lo, hi;
        #pragma unroll
        for (int j = 0; j < 8; ++j) { lo[j] = t[j]; hi[j] = t[8 + j]; }
        int sw = (c >> 2) & 1;
        bf16x8* dst = (bf16x8*)&lds[p * 16];
        dst[sw] = lo; dst[1 - sw] = hi;
    }
    bf16x8 wf[5];
    #pragma unroll
    for (int i = 0; i < 5; ++i)
        #pragma unroll
        for (int j = 0; j < 8; ++j) {
            int kk = 32 * i + 8 * g + j;
            int tap = kk >> 4, ci = kk & 15;
            short v = 0;
            if (tap < 9) v = f2bf(k[(m * 16 + ci) * 9 + tap]);
            wf[i][j] = v;
        }
    int off[5];
    #pragma unroll
    for (int i = 0; i < 5; ++i) {
        int tap = 2 * i + (g >> 1);
        if (tap > 8) tap = 8;
        int kh = tap / 3, kw = tap - kh * 3;
        int col = m + kw;
        int o = (kh * 34 + col) * 32 + (g & 1) * 16;
        off[i] = o ^ ((col & 4) << 2);
    }
    __syncthreads();
    const char* ldsb = (const char*)lds;
    const int coBase = g * 4;
    for (int hl8 = 0; hl8 < 8; ++hl8) {
        int hl = wv * 8 + hl8;
        int h = h0 + hl;
        bool hok = (h < HOUT);
        #pragma unroll
        for (int nh = 0; nh < 2; ++nh) {
            int wl = nh * 16;
            int tb = (hl * 34 + wl) * 32;
            f32x4 acc = {0.f, 0.f, 0.f, 0.f};
            #pragma unroll
            for (int i = 0; i < 5; ++i) {
                bf16x8 b = *(const bf16x8*)(ldsb + (tb + off[i]));
                acc = __builtin_amdgcn_mfma_f32_16x16x32_bf16(wf[i], b, acc, 0, 0, 0);
            }
            int w = w0 + wl + m;
            if (hok && w < WOUT) {
                float* op = out + h * WOUT + w;
                #pragma unroll
                for (int r = 0; r < 4; ++r)
                    op[(coBase + r) * PLANE_OUT] = acc[r];
            }
        }
    }
}

extern "C" void kernel_launch(void* const* d_in, const int* in_sizes, int n_in,
                              void* d_out, int out_size, void* d_ws, size_t ws_size,
                              hipStream_t stream) {
    const float* x = (const float*)d_in[0];
    const float* k = (const float*)d_in[1];
    float* out = (float*)d_out;
    if (ws_size >= WF_U32 * 4) {
        unsigned* wfbuf = (unsigned*)d_ws;
        wf_setup<<<dim3(1), dim3(64), 0, stream>>>(k, wfbuf);
        hipError_t e = hipFuncSetAttribute(
            reinterpret_cast<const void*>(conv3x3_gllb),
            hipFuncAttributeMaxDynamicSharedMemorySize, LDS_BYTES);
        if (e == hipSuccess) {
            conv3x3_gllb<<<dim3(4096), dim3(512), LDS_BYTES, stream>>>(x, wfbuf, out);
        } else {
            conv3x3_fused<<<dim3(4096), dim3(512), 0, stream>>>(x, wfbuf, out);
        }
    } else {
        conv3x3_mfma<<<dim3(4096), dim3(256), 0, stream>>>(x, k, out);
    }
}